// Round 6
// baseline (7133.582 us; speedup 1.0000x reference)
//
#include <hip/hip_runtime.h>
#include <hip/hip_bf16.h>
#include <cstddef>
#include <cstdint>

static constexpr int BB = 16;    // batch
static constexpr int TT = 1024;  // time steps
static constexpr int EE = 512;   // input dim
static constexpr int HH = 1024;  // hidden dim

// scan decomposition: 4 groups x 64 blocks; group owns 4 batches, all cols.
static constexpr int NG   = 4;
static constexpr int GBLK = 64;
static constexpr int BPG  = 4;
static constexpr int COLS = 16;

using u32 = unsigned int;
typedef float f32x4 __attribute__((ext_vector_type(4)));

// "not yet written" sentinel. h is always finite, so this NaN payload can
// never be produced as a real value.
static constexpr u32 PZ = 0x7FC0DEADu;

// ---------- storage-type helpers (fp32 or bf16 scratch for xr/xz) ----------
__device__ __forceinline__ float st_load(const float* p) { return *p; }
__device__ __forceinline__ float st_load(const __hip_bfloat16* p) { return __bfloat162float(*p); }
__device__ __forceinline__ void st_store(float* p, float v) { *p = v; }
__device__ __forceinline__ void st_store(__hip_bfloat16* p, float v) { *p = __float2bfloat16(v); }

// 16B device-scope (L1/L2-bypassing, LLC-coherent) load.
__device__ __forceinline__ void llc_load(f32x4& d, const f32x4* p) {
    asm volatile("global_load_dwordx4 %0, %1, off sc0 sc1" : "=v"(d) : "v"(p));
}
__device__ __forceinline__ void llc_drain() {
    asm volatile("s_waitcnt vmcnt(0)" ::: "memory");
    __builtin_amdgcn_sched_barrier(0);
}
__device__ __forceinline__ bool ok4(const f32x4 v) {
    return __float_as_uint(v[0]) != PZ && __float_as_uint(v[1]) != PZ &&
           __float_as_uint(v[2]) != PZ && __float_as_uint(v[3]) != PZ;
}

#define FMA4(ACC, S, W)                         \
    (ACC).x = fmaf((S), (W).x, (ACC).x);        \
    (ACC).y = fmaf((S), (W).y, (ACC).y);        \
    (ACC).z = fmaf((S), (W).z, (ACC).z);        \
    (ACC).w = fmaf((S), (W).w, (ACC).w);

// =====================================================================
// Phase 1: xr = x@Wxr+br -> ws, xz = x@Wxz+bz -> ws, xi = x@Wi+b -> d_out
// Also zeroes the scan kernel's barrier counters (block (0,0)).
// =====================================================================
template <typename ST>
__global__ __launch_bounds__(256) void proj_kernel(
    const float* __restrict__ x,
    const float* __restrict__ Wxr, const float* __restrict__ br,
    const float* __restrict__ Wxz, const float* __restrict__ bz,
    const float* __restrict__ Wi,  const float* __restrict__ bi,
    ST* __restrict__ xr_out, ST* __restrict__ xz_out, float* __restrict__ xi_out,
    u32* __restrict__ bar)
{
    __shared__ float xT[16][68];
    __shared__ float wB[3][16][64];

    const int tid = threadIdx.x;
    if (blockIdx.x == 0 && blockIdx.y == 0) bar[tid] = 0u;

    const int tx = tid & 15, ty = tid >> 4;
    const int m0 = blockIdx.y * 64, n0 = blockIdx.x * 64;
    const float* Wg[3] = {Wxr, Wxz, Wi};

    float4 acc[3][4];
#pragma unroll
    for (int g = 0; g < 3; ++g)
#pragma unroll
        for (int i = 0; i < 4; ++i) acc[g][i] = make_float4(0.f, 0.f, 0.f, 0.f);

    const int xrow = tid >> 2, xk = (tid & 3) * 4;
    const int wk = tid >> 4, wn = (tid & 15) * 4;

    for (int k0 = 0; k0 < EE; k0 += 16) {
        float4 xv = *(const float4*)(x + (size_t)(m0 + xrow) * EE + k0 + xk);
        xT[xk + 0][xrow] = xv.x;
        xT[xk + 1][xrow] = xv.y;
        xT[xk + 2][xrow] = xv.z;
        xT[xk + 3][xrow] = xv.w;
#pragma unroll
        for (int g = 0; g < 3; ++g) {
            float4 wv = *(const float4*)(Wg[g] + (size_t)(k0 + wk) * HH + n0 + wn);
            *(float4*)&wB[g][wk][wn] = wv;
        }
        __syncthreads();
#pragma unroll
        for (int kk = 0; kk < 16; ++kk) {
            float4 a  = *(const float4*)&xT[kk][ty * 4];
            float4 w0 = *(const float4*)&wB[0][kk][tx * 4];
            float4 w1 = *(const float4*)&wB[1][kk][tx * 4];
            float4 w2 = *(const float4*)&wB[2][kk][tx * 4];
            float as[4] = {a.x, a.y, a.z, a.w};
#pragma unroll
            for (int i = 0; i < 4; ++i) {
                FMA4(acc[0][i], as[i], w0);
                FMA4(acc[1][i], as[i], w1);
                FMA4(acc[2][i], as[i], w2);
            }
        }
        __syncthreads();
    }

    float4 bv0 = *(const float4*)(br + n0 + tx * 4);
    float4 bv1 = *(const float4*)(bz + n0 + tx * 4);
    float4 bv2 = *(const float4*)(bi + n0 + tx * 4);
#pragma unroll
    for (int i = 0; i < 4; ++i) {
        size_t m = (size_t)m0 + ty * 4 + i;
        size_t off = m * HH + n0 + tx * 4;
        float4 v0 = acc[0][i]; v0.x += bv0.x; v0.y += bv0.y; v0.z += bv0.z; v0.w += bv0.w;
        float4 v1 = acc[1][i]; v1.x += bv1.x; v1.y += bv1.y; v1.z += bv1.z; v1.w += bv1.w;
        float4 v2 = acc[2][i]; v2.x += bv2.x; v2.y += bv2.y; v2.z += bv2.z; v2.w += bv2.w;
        st_store(xr_out + off + 0, v0.x); st_store(xr_out + off + 1, v0.y);
        st_store(xr_out + off + 2, v0.z); st_store(xr_out + off + 3, v0.w);
        st_store(xz_out + off + 0, v1.x); st_store(xz_out + off + 1, v1.y);
        st_store(xz_out + off + 2, v1.z); st_store(xz_out + off + 3, v1.w);
        *(float4*)(xi_out + off) = v2;
    }
}

// =====================================================================
// 8-lane allreduce within each half-row: quad xor1, xor2, then
// row_half_mirror (0x141, lane i <-> 7-i within each 8-group; symmetric,
// direction-safe). All 8 lanes end with the group sum.
// =====================================================================
__device__ __forceinline__ float red8_allreduce(float v) {
    int y;
    y = __builtin_amdgcn_update_dpp(0, __float_as_int(v), 0xB1, 0xF, 0xF, true);  // quad_perm [1,0,3,2]
    v += __int_as_float(y);
    y = __builtin_amdgcn_update_dpp(0, __float_as_int(v), 0x4E, 0xF, 0xF, true);  // quad_perm [2,3,0,1]
    v += __int_as_float(y);
    y = __builtin_amdgcn_update_dpp(0, __float_as_int(v), 0x141, 0xF, 0xF, true); // row_half_mirror
    v += __int_as_float(y);
    return v;
}

// =====================================================================
// One-time flat per-group barrier (orders init before the main loop).
// =====================================================================
__device__ __forceinline__ void xbar(u32* ctr, unsigned target) {
    __syncthreads();
    if (threadIdx.x == 0) {
        asm volatile("s_waitcnt vmcnt(0)" ::: "memory");
        __builtin_amdgcn_sched_barrier(0);
        __hip_atomic_fetch_add(ctr, 1u, __ATOMIC_RELAXED, __HIP_MEMORY_SCOPE_AGENT);
        while (__hip_atomic_load(ctr, __ATOMIC_RELAXED, __HIP_MEMORY_SCOPE_AGENT) < target) {
            __builtin_amdgcn_s_sleep(1);
        }
        __builtin_amdgcn_sched_barrier(0);
    }
    __syncthreads();
}

// =====================================================================
// Phase 2: persistent barrier-free scan. 4 groups x 64 blocks x 512 thr.
// NaN-sentinel rotating 4-buffer h exchange (see R5). Changes this round:
//  (1) re-poison B(t+2) EARLY (right after staging; safe since poll success
//      at t proves all blocks passed step t-1, so all B(t-2) reads done) —
//      the tail's vmcnt(0) drain before the h release-store becomes free.
//  (2) padded LDS slot map p = s + (s>>2): reads are 8 distinct banks x
//      8-lane broadcast (conflict-free), writes 2-way (free).
//  (3) lane split (cg8, kl8): 6 units x 16 k per lane (weights still 96),
//      reduce over 8 lanes = 3 DPP steps -> 144 reduce insts vs 384.
// =====================================================================
template <typename ST>
__global__ __launch_bounds__(512, 1) void scan_kernel(
    const ST* __restrict__ xr, const ST* __restrict__ xz,
    const float* __restrict__ Whr, const float* __restrict__ Whz, const float* __restrict__ Wh,
    float* __restrict__ out,      // d_out: xi pre-activations, overwritten with h
    float* __restrict__ hbuf,     // [4][16][1024] fp32 rotating exchange buffers
    u32* __restrict__ bar)
{
    __shared__ f32x4 hsx[8][4][40];      // [wave][batch][padded slot] 20KB
    __shared__ float red[8][48][5];      // [wave][ugc][b4(+pad)]
    __shared__ float pre[48][4];         // [ugc = gate*16+col][b4]

    const int tid = threadIdx.x, bid = blockIdx.x;
    const int lane = tid & 63, wv = tid >> 6;       // wv 0..7
    const int cg8 = lane >> 3, kl8 = lane & 7;      // 8 unit-groups x 8 k-lanes
    const int group = bid >> 6, gb = bid & 63;
    const int n0 = gb * COLS;
    u32* ctr = bar + group * 64;

    // ---- recurrent weights -> registers: 6 units x 16 k = 96 f32 ----
    float wreg[6][16];
    {
        const float* WG[3] = {Whr, Whz, Wh};
        const int k0 = wv * 128 + kl8 * 16;
#pragma unroll
        for (int u = 0; u < 6; ++u) {
            int ugc = cg8 * 6 + u;                  // 0..47: gate=ugc>>4, col=ugc&15
            const float* W = WG[ugc >> 4];
            int col = n0 + (ugc & 15);
#pragma unroll
            for (int j = 0; j < 16; ++j)
                wreg[u][j] = W[(size_t)(k0 + j) * HH + col];
        }
    }

    const float pzf = __uint_as_float(PZ);
    const int tb4 = tid >> 4, tc = tid & 15;        // elementwise mapping (tid<64)
    const int tbg = group * BPG + tb4;
    const int coln = n0 + tc;

    // ---- init: zero B0 (h_0), poison B1..B3; prefetch t=0 operands ----
    float pxr = 0.f, pxz = 0.f, pxi = 0.f, hprev = 0.f;
    if (tid < 64) {
        float* b0 = hbuf + group * (BPG * HH) + tb4 * HH + coln;
        __hip_atomic_store(b0,         0.f, __ATOMIC_RELAXED, __HIP_MEMORY_SCOPE_AGENT);
        __hip_atomic_store(b0 + 16384, pzf, __ATOMIC_RELAXED, __HIP_MEMORY_SCOPE_AGENT);
        __hip_atomic_store(b0 + 32768, pzf, __ATOMIC_RELAXED, __HIP_MEMORY_SCOPE_AGENT);
        __hip_atomic_store(b0 + 49152, pzf, __ATOMIC_RELAXED, __HIP_MEMORY_SCOPE_AGENT);
        size_t idx0 = (size_t)(tbg * TT) * HH + coln;
        pxr = st_load(xr + idx0); pxz = st_load(xz + idx0); pxi = out[idx0];
    }
    xbar(ctr, GBLK);

    // staging: lane loads 2 adjacent granules of its wave window (batch b_ld),
    // rotated by gb to spread LLC banks. Padded phys slot p = s + (s>>2).
    const int b_ld = lane >> 4;
    const int m16 = ((lane & 15) + gb) & 15;
    const int s_rot = 2 * m16;                      // even slot in [0,32)
    const int p_w = s_rot + (s_rot >> 2);           // write phys (p, p+1)
    const int g_base = group * 1024 + b_ld * 256 + wv * 32 + s_rot;
    const int p_r = 5 * kl8;                        // read phys base (4 slots)

    for (int t = 0; t < TT; ++t) {
        // ---- poll own granules until non-poison; stage to LDS (wave-local) ----
        {
            const f32x4* p = (const f32x4*)hbuf + (size_t)(t & 3) * 4096 + g_base;
            f32x4 va, vb;
            for (;;) {
                llc_load(va, p); llc_load(vb, p + 1); llc_drain();
                if (ok4(va) && ok4(vb)) break;
                __builtin_amdgcn_s_sleep(1);
            }
            hsx[wv][b_ld][p_w]     = va;
            hsx[wv][b_ld][p_w + 1] = vb;
            asm volatile("s_waitcnt lgkmcnt(0)" ::: "memory");
            __builtin_amdgcn_sched_barrier(0);
        }

        // ---- EARLY re-poison B(t+2): acks during the ~2us of compute below,
        // so the tail's vmcnt(0) drain is free. Safety: poll success at t
        // implies every block stored h_t, hence passed all B(t-2) reads. ----
        if (tid < 64 && t + 2 < TT) {
            __hip_atomic_store(hbuf + (size_t)((t + 2) & 3) * 16384
                               + group * (BPG * HH) + tb4 * HH + coln,
                               pzf, __ATOMIC_RELAXED, __HIP_MEMORY_SCOPE_AGENT);
        }

        // ---- partial dots: 4 batches x 6 units x 16 k = 384 FMA/thread ----
        float pacc[4][6];
#pragma unroll
        for (int b = 0; b < 4; ++b)
#pragma unroll
            for (int u = 0; u < 6; ++u) pacc[b][u] = 0.f;

#pragma unroll
        for (int b = 0; b < 4; ++b) {
            f32x4 h0 = hsx[wv][b][p_r + 0];
            f32x4 h1 = hsx[wv][b][p_r + 1];
            f32x4 h2 = hsx[wv][b][p_r + 2];
            f32x4 h3 = hsx[wv][b][p_r + 3];
#pragma unroll
            for (int u = 0; u < 6; ++u) {
                float a = pacc[b][u];
                a = fmaf(h0[0], wreg[u][0], a);
                a = fmaf(h0[1], wreg[u][1], a);
                a = fmaf(h0[2], wreg[u][2], a);
                a = fmaf(h0[3], wreg[u][3], a);
                a = fmaf(h1[0], wreg[u][4], a);
                a = fmaf(h1[1], wreg[u][5], a);
                a = fmaf(h1[2], wreg[u][6], a);
                a = fmaf(h1[3], wreg[u][7], a);
                a = fmaf(h2[0], wreg[u][8], a);
                a = fmaf(h2[1], wreg[u][9], a);
                a = fmaf(h2[2], wreg[u][10], a);
                a = fmaf(h2[3], wreg[u][11], a);
                a = fmaf(h3[0], wreg[u][12], a);
                a = fmaf(h3[1], wreg[u][13], a);
                a = fmaf(h3[2], wreg[u][14], a);
                a = fmaf(h3[3], wreg[u][15], a);
                pacc[b][u] = a;
            }
        }

        // ---- reduce over the 8 k-lanes of each group ----
#pragma unroll
        for (int b = 0; b < 4; ++b)
#pragma unroll
            for (int u = 0; u < 6; ++u) pacc[b][u] = red8_allreduce(pacc[b][u]);

        if (kl8 == 0) {
#pragma unroll
            for (int b = 0; b < 4; ++b)
#pragma unroll
                for (int u = 0; u < 6; ++u) red[wv][cg8 * 6 + u][b] = pacc[b][u];
        }
        __syncthreads();                 // S1: red ready

        // ---- combine 8 waves -> 192 gate pre-activations ----
        if (tid < 192) {
            int b4 = tid & 3, ugc = tid >> 2;
            float s = 0.f;
#pragma unroll
            for (int w = 0; w < 8; ++w) s += red[w][ugc][b4];
            pre[ugc][b4] = s;
        }
        __syncthreads();                 // S2: pre ready

        // ---- elementwise GRU update; h-store is the next step's signal ----
        if (tid < 64) {
            float dr = pre[tc][tb4], dz = pre[16 + tc][tb4], dh = pre[32 + tc][tb4];
            float r = 1.f / (1.f + expf(-(dr + pxr)));
            float z = 1.f / (1.f + expf(-(dz + pxz)));
            float cand = tanhf(fmaf(r, dh, pxi));
            float hnew = fmaf(z, hprev - cand, cand);         // z*h + (1-z)*cand
            hprev = hnew;                                     // carried in register
            // drain orders poison (issued ~2us ago, already acked) < h-store
            asm volatile("s_waitcnt vmcnt(0)" ::: "memory");
            __builtin_amdgcn_sched_barrier(0);
            if (t + 1 < TT) {
                __hip_atomic_store(hbuf + (size_t)((t + 1) & 3) * 16384
                                   + group * (BPG * HH) + tb4 * HH + coln,
                                   hnew, __ATOMIC_RELAXED, __HIP_MEMORY_SCOPE_AGENT);
            }
            size_t idx = (size_t)(tbg * TT + t) * HH + coln;
            out[idx] = hnew;
            if (t + 1 < TT) {            // self-prefetch t+1 (off critical path)
                size_t idx2 = idx + HH;
                pxr = st_load(xr + idx2); pxz = st_load(xz + idx2); pxi = out[idx2];
            }
        }
        // no block barrier: waves proceed straight to polling h_{t+1}
    }
}

__global__ void sentinel_kernel(float* out) {
    if (threadIdx.x == 0 && blockIdx.x == 0) out[0] = 12345.0f;
}

// =====================================================================
extern "C" void kernel_launch(void* const* d_in, const int* in_sizes, int n_in,
                              void* d_out, int out_size, void* d_ws, size_t ws_size,
                              hipStream_t stream) {
    const float* x   = (const float*)d_in[0];
    const float* Wxr = (const float*)d_in[1];
    const float* Whr = (const float*)d_in[2];
    const float* br  = (const float*)d_in[3];
    const float* Wxz = (const float*)d_in[4];
    const float* Whz = (const float*)d_in[5];
    const float* bz  = (const float*)d_in[6];
    const float* Wi  = (const float*)d_in[7];
    const float* Wh  = (const float*)d_in[8];
    const float* bb  = (const float*)d_in[9];
    float* out = (float*)d_out;

    const size_t BTH = (size_t)BB * TT * HH;
    const size_t HBUF_ELTS = (size_t)4 * BB * HH;      // 4 rotating buffers
    const size_t BAR_BYTES = 4096;
    const size_t need_f32 = 2 * BTH * sizeof(float) + HBUF_ELTS * sizeof(float) + BAR_BYTES;
    const size_t need_b16 = 2 * BTH * sizeof(__hip_bfloat16) + HBUF_ELTS * sizeof(float) + BAR_BYTES;

    dim3 pgrid(HH / 64, (BB * TT) / 64);   // (16, 256)

    if (ws_size >= need_f32) {
        float* xr = (float*)d_ws;
        float* xz = xr + BTH;
        float* hb = xz + BTH;
        u32* bar = (u32*)(hb + HBUF_ELTS);
        proj_kernel<float><<<pgrid, 256, 0, stream>>>(x, Wxr, br, Wxz, bz, Wi, bb, xr, xz, out, bar);
        const float* xrc = xr; const float* xzc = xz;
        void* args[8] = {(void*)&xrc, (void*)&xzc, (void*)&Whr, (void*)&Whz,
                         (void*)&Wh, (void*)&out, (void*)&hb, (void*)&bar};
        hipLaunchCooperativeKernel((void*)scan_kernel<float>, dim3(256), dim3(512),
                                   args, 0, stream);
    } else if (ws_size >= need_b16) {
        __hip_bfloat16* xr = (__hip_bfloat16*)d_ws;
        __hip_bfloat16* xz = xr + BTH;
        float* hb = (float*)(xz + BTH);
        u32* bar = (u32*)(hb + HBUF_ELTS);
        proj_kernel<__hip_bfloat16><<<pgrid, 256, 0, stream>>>(x, Wxr, br, Wxz, bz, Wi, bb, xr, xz, out, bar);
        const __hip_bfloat16* xrc = xr; const __hip_bfloat16* xzc = xz;
        void* args[8] = {(void*)&xrc, (void*)&xzc, (void*)&Whr, (void*)&Whz,
                         (void*)&Wh, (void*)&out, (void*)&hb, (void*)&bar};
        hipLaunchCooperativeKernel((void*)scan_kernel<__hip_bfloat16>, dim3(256), dim3(512),
                                   args, 0, stream);
    } else {
        sentinel_kernel<<<1, 64, 0, stream>>>(out);
    }
}

// Round 9
// 5191.985 us; speedup vs baseline: 1.3740x; 1.3740x over previous
//
#include <hip/hip_runtime.h>
#include <hip/hip_bf16.h>
#include <cstddef>
#include <cstdint>

static constexpr int BB = 16;    // batch
static constexpr int TT = 1024;  // time steps
static constexpr int EE = 512;   // input dim
static constexpr int HH = 1024;  // hidden dim

// scan decomposition: 4 groups x 64 blocks; group owns 4 batches, all cols.
static constexpr int NG   = 4;
static constexpr int GBLK = 64;
static constexpr int BPG  = 4;
static constexpr int COLS = 16;

using u32 = unsigned int;
typedef float f32x4 __attribute__((ext_vector_type(4)));

// "not yet written" sentinel. h is always finite, so this NaN payload can
// never be produced as a real value.
static constexpr u32 PZ = 0x7FC0DEADu;

// ---------- storage-type helpers (fp32 or bf16 scratch for xr/xz) ----------
__device__ __forceinline__ float st_load(const float* p) { return *p; }
__device__ __forceinline__ float st_load(const __hip_bfloat16* p) { return __bfloat162float(*p); }
__device__ __forceinline__ void st_store(float* p, float v) { *p = v; }
__device__ __forceinline__ void st_store(__hip_bfloat16* p, float v) { *p = __float2bfloat16(v); }

// 16B device-scope (L1/L2-bypassing, LLC-coherent) load.
__device__ __forceinline__ void llc_load(f32x4& d, const f32x4* p) {
    asm volatile("global_load_dwordx4 %0, %1, off sc0 sc1" : "=v"(d) : "v"(p));
}
__device__ __forceinline__ void llc_drain() {
    asm volatile("s_waitcnt vmcnt(0)" ::: "memory");
    __builtin_amdgcn_sched_barrier(0);
}
__device__ __forceinline__ bool ok4(const f32x4 v) {
    return __float_as_uint(v[0]) != PZ && __float_as_uint(v[1]) != PZ &&
           __float_as_uint(v[2]) != PZ && __float_as_uint(v[3]) != PZ;
}

#define FMA4(ACC, S, W)                         \
    (ACC).x = fmaf((S), (W).x, (ACC).x);        \
    (ACC).y = fmaf((S), (W).y, (ACC).y);        \
    (ACC).z = fmaf((S), (W).z, (ACC).z);        \
    (ACC).w = fmaf((S), (W).w, (ACC).w);

// =====================================================================
// Phase 1: xr = x@Wxr+br -> ws, xz = x@Wxz+bz -> ws, xi = x@Wi+b -> d_out
// Also zeroes the scan kernel's barrier counters (block (0,0)).
// =====================================================================
template <typename ST>
__global__ __launch_bounds__(256) void proj_kernel(
    const float* __restrict__ x,
    const float* __restrict__ Wxr, const float* __restrict__ br,
    const float* __restrict__ Wxz, const float* __restrict__ bz,
    const float* __restrict__ Wi,  const float* __restrict__ bi,
    ST* __restrict__ xr_out, ST* __restrict__ xz_out, float* __restrict__ xi_out,
    u32* __restrict__ bar)
{
    __shared__ float xT[16][68];
    __shared__ float wB[3][16][64];

    const int tid = threadIdx.x;
    if (blockIdx.x == 0 && blockIdx.y == 0) bar[tid] = 0u;

    const int tx = tid & 15, ty = tid >> 4;
    const int m0 = blockIdx.y * 64, n0 = blockIdx.x * 64;
    const float* Wg[3] = {Wxr, Wxz, Wi};

    float4 acc[3][4];
#pragma unroll
    for (int g = 0; g < 3; ++g)
#pragma unroll
        for (int i = 0; i < 4; ++i) acc[g][i] = make_float4(0.f, 0.f, 0.f, 0.f);

    const int xrow = tid >> 2, xk = (tid & 3) * 4;
    const int wk = tid >> 4, wn = (tid & 15) * 4;

    for (int k0 = 0; k0 < EE; k0 += 16) {
        float4 xv = *(const float4*)(x + (size_t)(m0 + xrow) * EE + k0 + xk);
        xT[xk + 0][xrow] = xv.x;
        xT[xk + 1][xrow] = xv.y;
        xT[xk + 2][xrow] = xv.z;
        xT[xk + 3][xrow] = xv.w;
#pragma unroll
        for (int g = 0; g < 3; ++g) {
            float4 wv = *(const float4*)(Wg[g] + (size_t)(k0 + wk) * HH + n0 + wn);
            *(float4*)&wB[g][wk][wn] = wv;
        }
        __syncthreads();
#pragma unroll
        for (int kk = 0; kk < 16; ++kk) {
            float4 a  = *(const float4*)&xT[kk][ty * 4];
            float4 w0 = *(const float4*)&wB[0][kk][tx * 4];
            float4 w1 = *(const float4*)&wB[1][kk][tx * 4];
            float4 w2 = *(const float4*)&wB[2][kk][tx * 4];
            float as[4] = {a.x, a.y, a.z, a.w};
#pragma unroll
            for (int i = 0; i < 4; ++i) {
                FMA4(acc[0][i], as[i], w0);
                FMA4(acc[1][i], as[i], w1);
                FMA4(acc[2][i], as[i], w2);
            }
        }
        __syncthreads();
    }

    float4 bv0 = *(const float4*)(br + n0 + tx * 4);
    float4 bv1 = *(const float4*)(bz + n0 + tx * 4);
    float4 bv2 = *(const float4*)(bi + n0 + tx * 4);
#pragma unroll
    for (int i = 0; i < 4; ++i) {
        size_t m = (size_t)m0 + ty * 4 + i;
        size_t off = m * HH + n0 + tx * 4;
        float4 v0 = acc[0][i]; v0.x += bv0.x; v0.y += bv0.y; v0.z += bv0.z; v0.w += bv0.w;
        float4 v1 = acc[1][i]; v1.x += bv1.x; v1.y += bv1.y; v1.z += bv1.z; v1.w += bv1.w;
        float4 v2 = acc[2][i]; v2.x += bv2.x; v2.y += bv2.y; v2.z += bv2.z; v2.w += bv2.w;
        st_store(xr_out + off + 0, v0.x); st_store(xr_out + off + 1, v0.y);
        st_store(xr_out + off + 2, v0.z); st_store(xr_out + off + 3, v0.w);
        st_store(xz_out + off + 0, v1.x); st_store(xz_out + off + 1, v1.y);
        st_store(xz_out + off + 2, v1.z); st_store(xz_out + off + 3, v1.w);
        *(float4*)(xi_out + off) = v2;
    }
}

// =====================================================================
// DPP all-reduce over each row of 16 lanes (sum). Validated R2-R6.
// =====================================================================
__device__ __forceinline__ float row16_allreduce(float v) {
    int y;
    y = __builtin_amdgcn_update_dpp(0, __float_as_int(v), 0xB1, 0xF, 0xF, true);  // quad_perm [1,0,3,2]
    v += __int_as_float(y);
    y = __builtin_amdgcn_update_dpp(0, __float_as_int(v), 0x4E, 0xF, 0xF, true);  // quad_perm [2,3,0,1]
    v += __int_as_float(y);
    y = __builtin_amdgcn_update_dpp(0, __float_as_int(v), 0x124, 0xF, 0xF, true); // row_ror:4
    v += __int_as_float(y);
    y = __builtin_amdgcn_update_dpp(0, __float_as_int(v), 0x128, 0xF, 0xF, true); // row_ror:8
    v += __int_as_float(y);
    return v;
}

// =====================================================================
// One-time flat per-group barrier (orders init before the main loop).
// =====================================================================
__device__ __forceinline__ void xbar(u32* ctr, unsigned target) {
    __syncthreads();
    if (threadIdx.x == 0) {
        asm volatile("s_waitcnt vmcnt(0)" ::: "memory");
        __builtin_amdgcn_sched_barrier(0);
        __hip_atomic_fetch_add(ctr, 1u, __ATOMIC_RELAXED, __HIP_MEMORY_SCOPE_AGENT);
        while (__hip_atomic_load(ctr, __ATOMIC_RELAXED, __HIP_MEMORY_SCOPE_AGENT) < target) {
            __builtin_amdgcn_s_sleep(1);
        }
        __builtin_amdgcn_sched_barrier(0);
    }
    __syncthreads();
}

// =====================================================================
// Phase 2: persistent barrier-free scan — EXACT R5 structure (passing,
// 4.68us/step) with ONE change: the B(t+2) re-poison is issued EARLY,
// immediately after this thread's poll succeeds (validated correct in R6),
// instead of between reduce and S1. The tail's vmcnt(0) drain before the
// h release-store then waits on a ~2us-old store -> free.
// Safety (unchanged): poll success at t proves all blocks stored h_t =>
// all passed step t-1 => all step t-2 reads of epoch (t+2)&3 are complete.
// =====================================================================
template <typename ST>
__global__ __launch_bounds__(512, 1) void scan_kernel(
    const ST* __restrict__ xr, const ST* __restrict__ xz,
    const float* __restrict__ Whr, const float* __restrict__ Whz, const float* __restrict__ Wh,
    float* __restrict__ out,      // d_out: xi pre-activations, overwritten with h
    float* __restrict__ hbuf,     // [4][16][1024] fp32 rotating exchange epochs
    u32* __restrict__ bar)
{
    __shared__ f32x4 hsx[8][4][32];      // [wave][batch][slot] 16KB, wave-private
    __shared__ float red[8][4][48];      // [wave][cgg][b4*12+u]
    __shared__ float pre[48][4];         // [gate*16+col][b4]

    const int tid = threadIdx.x, bid = blockIdx.x;
    const int lane = tid & 63, wv = tid >> 6;       // wv 0..7
    const int cgg = lane >> 4, kslo = lane & 15;
    const int ks = wv * 16 + kslo;                  // 0..127
    const int group = bid >> 6, gb = bid & 63;
    const int n0 = gb * COLS;
    u32* ctr = bar + group * 64;

    // ---- recurrent weights -> registers: 12 units x 8 k ----
    float wreg[12][8];
    {
        const float* WG[3] = {Whr, Whz, Wh};
#pragma unroll
        for (int u = 0; u < 12; ++u) {
            int ugc = cgg * 12 + u;                 // 0..47: gate=ugc>>4, col=ugc&15
            const float* W = WG[ugc >> 4];
            int col = n0 + (ugc & 15);
#pragma unroll
            for (int j = 0; j < 8; ++j)
                wreg[u][j] = W[(size_t)(ks * 8 + j) * HH + col];
        }
    }

    const float pzf = __uint_as_float(PZ);
    const int tb4 = tid >> 4, tc = tid & 15;        // elementwise mapping (tid<64)
    const int tbg = group * BPG + tb4;
    const int coln = n0 + tc;

    // ---- init: zero B0 (h_0 = 0), poison B1..B3; prefetch t=0 operands ----
    float pxr = 0.f, pxz = 0.f, pxi = 0.f, hprev = 0.f;
    if (tid < 64) {
        float* b0 = hbuf + group * (BPG * HH) + tb4 * HH + coln;
        __hip_atomic_store(b0,         0.f, __ATOMIC_RELAXED, __HIP_MEMORY_SCOPE_AGENT);
        __hip_atomic_store(b0 + 16384, pzf, __ATOMIC_RELAXED, __HIP_MEMORY_SCOPE_AGENT);
        __hip_atomic_store(b0 + 32768, pzf, __ATOMIC_RELAXED, __HIP_MEMORY_SCOPE_AGENT);
        __hip_atomic_store(b0 + 49152, pzf, __ATOMIC_RELAXED, __HIP_MEMORY_SCOPE_AGENT);
        size_t idx0 = (size_t)(tbg * TT) * HH + coln;
        pxr = st_load(xr + idx0); pxz = st_load(xz + idx0); pxi = out[idx0];
    }
    xbar(ctr, GBLK);   // one-time: init visible before anyone polls

    // staging assignment: lane loads 2 adjacent slots of wave's 32-slot
    // window (per its batch), rotated by gb to spread LLC banks.
    const int b_ld = lane >> 4;
    const int s_rot = (((lane & 15) + (gb & 15)) * 2) & 31;   // even, in [0,32)

    for (int t = 0; t < TT; ++t) {
        // ---- stage h_t: poll own k-slice until non-poison, wave-local sync ----
        {
            const f32x4* p = (const f32x4*)hbuf + (size_t)(t & 3) * 4096
                             + group * 1024 + b_ld * 256 + wv * 32 + s_rot;
            f32x4 va, vb;
            for (;;) {
                llc_load(va, p); llc_load(vb, p + 1); llc_drain();
                if (ok4(va) && ok4(vb)) break;
                __builtin_amdgcn_s_sleep(1);
            }
            hsx[wv][b_ld][s_rot]     = va;
            hsx[wv][b_ld][s_rot + 1] = vb;
            asm volatile("s_waitcnt lgkmcnt(0)" ::: "memory");  // wave-local LDS visibility
            __builtin_amdgcn_sched_barrier(0);
        }

        // ---- EARLY re-poison B(t+2): issued now so the ack lands during
        // the FMA+reduce+combine below; the tail's vmcnt(0) drain becomes
        // free. Correctness of this placement validated in R6. ----
        if (tid < 64 && t + 2 < TT) {
            __hip_atomic_store(hbuf + (size_t)((t + 2) & 3) * 16384
                               + group * (BPG * HH) + tb4 * HH + coln,
                               pzf, __ATOMIC_RELAXED, __HIP_MEMORY_SCOPE_AGENT);
        }

        // ---- partial dots: 4 batches x 12 units x 8 k = 384 FMA/thread ----
        float pacc[4][12];
#pragma unroll
        for (int b = 0; b < 4; ++b)
#pragma unroll
            for (int u = 0; u < 12; ++u) pacc[b][u] = 0.f;

#pragma unroll
        for (int b = 0; b < 4; ++b) {
            f32x4 ha = hsx[wv][b][2 * kslo];
            f32x4 hb = hsx[wv][b][2 * kslo + 1];
#pragma unroll
            for (int u = 0; u < 12; ++u) {
                float a = pacc[b][u];
                a = fmaf(ha[0], wreg[u][0], a);
                a = fmaf(ha[1], wreg[u][1], a);
                a = fmaf(ha[2], wreg[u][2], a);
                a = fmaf(ha[3], wreg[u][3], a);
                a = fmaf(hb[0], wreg[u][4], a);
                a = fmaf(hb[1], wreg[u][5], a);
                a = fmaf(hb[2], wreg[u][6], a);
                a = fmaf(hb[3], wreg[u][7], a);
                pacc[b][u] = a;
            }
        }

        // ---- reduce over kslo (16 lanes per row) ----
#pragma unroll
        for (int b = 0; b < 4; ++b)
#pragma unroll
            for (int u = 0; u < 12; ++u) pacc[b][u] = row16_allreduce(pacc[b][u]);

        if (kslo == 0) {
#pragma unroll
            for (int b = 0; b < 4; ++b)
#pragma unroll
                for (int u = 0; u < 12; ++u) red[wv][cgg][b * 12 + u] = pacc[b][u];
        }
        __syncthreads();                 // S1: red ready

        // ---- combine 8 waves -> 192 gate pre-activations ----
        if (tid < 192) {
            int b4 = tid & 3, ugc = tid >> 2;        // ugc in [0,48)
            int cq = ugc / 12, u = ugc - cq * 12;
            float s = 0.f;
#pragma unroll
            for (int w = 0; w < 8; ++w) s += red[w][cq][b4 * 12 + u];
            pre[ugc][b4] = s;
        }
        __syncthreads();                 // S2: pre ready

        // ---- elementwise GRU update; h-store is the next step's signal ----
        if (tid < 64) {
            float dr = pre[tc][tb4], dz = pre[16 + tc][tb4], dh = pre[32 + tc][tb4];
            float r = 1.f / (1.f + expf(-(dr + pxr)));
            float z = 1.f / (1.f + expf(-(dz + pxz)));
            float cand = tanhf(fmaf(r, dh, pxi));
            float hnew = fmaf(z, hprev - cand, cand);         // z*h + (1-z)*cand
            hprev = hnew;                                     // carried in register
            // drain: orders the (long-acked) early poison before the h-store
            asm volatile("s_waitcnt vmcnt(0)" ::: "memory");
            __builtin_amdgcn_sched_barrier(0);
            if (t + 1 < TT) {
                __hip_atomic_store(hbuf + (size_t)((t + 1) & 3) * 16384
                                   + group * (BPG * HH) + tb4 * HH + coln,
                                   hnew, __ATOMIC_RELAXED, __HIP_MEMORY_SCOPE_AGENT);
            }
            size_t idx = (size_t)(tbg * TT + t) * HH + coln;
            out[idx] = hnew;
            // self-prefetch t+1 operands (off critical path; lands during next step)
            if (t + 1 < TT) {
                size_t idx2 = idx + HH;
                pxr = st_load(xr + idx2); pxz = st_load(xz + idx2); pxi = out[idx2];
            }
        }
        // no block barrier: waves proceed straight to polling h_{t+1}
    }
}

__global__ void sentinel_kernel(float* out) {
    if (threadIdx.x == 0 && blockIdx.x == 0) out[0] = 12345.0f;
}

// =====================================================================
extern "C" void kernel_launch(void* const* d_in, const int* in_sizes, int n_in,
                              void* d_out, int out_size, void* d_ws, size_t ws_size,
                              hipStream_t stream) {
    const float* x   = (const float*)d_in[0];
    const float* Wxr = (const float*)d_in[1];
    const float* Whr = (const float*)d_in[2];
    const float* br  = (const float*)d_in[3];
    const float* Wxz = (const float*)d_in[4];
    const float* Whz = (const float*)d_in[5];
    const float* bz  = (const float*)d_in[6];
    const float* Wi  = (const float*)d_in[7];
    const float* Wh  = (const float*)d_in[8];
    const float* bb  = (const float*)d_in[9];
    float* out = (float*)d_out;

    const size_t BTH = (size_t)BB * TT * HH;
    const size_t HBUF_ELTS = (size_t)4 * BB * HH;      // 4 rotating epochs
    const size_t BAR_BYTES = 4096;
    const size_t need_f32 = 2 * BTH * sizeof(float) + HBUF_ELTS * sizeof(float) + BAR_BYTES;
    const size_t need_b16 = 2 * BTH * sizeof(__hip_bfloat16) + HBUF_ELTS * sizeof(float) + BAR_BYTES;

    dim3 pgrid(HH / 64, (BB * TT) / 64);   // (16, 256)

    if (ws_size >= need_f32) {
        float* xr = (float*)d_ws;
        float* xz = xr + BTH;
        float* hb = xz + BTH;
        u32* bar = (u32*)(hb + HBUF_ELTS);
        proj_kernel<float><<<pgrid, 256, 0, stream>>>(x, Wxr, br, Wxz, bz, Wi, bb, xr, xz, out, bar);
        const float* xrc = xr; const float* xzc = xz;
        void* args[8] = {(void*)&xrc, (void*)&xzc, (void*)&Whr, (void*)&Whz,
                         (void*)&Wh, (void*)&out, (void*)&hb, (void*)&bar};
        hipLaunchCooperativeKernel((void*)scan_kernel<float>, dim3(256), dim3(512),
                                   args, 0, stream);
    } else if (ws_size >= need_b16) {
        __hip_bfloat16* xr = (__hip_bfloat16*)d_ws;
        __hip_bfloat16* xz = xr + BTH;
        float* hb = (float*)(xz + BTH);
        u32* bar = (u32*)(hb + HBUF_ELTS);
        proj_kernel<__hip_bfloat16><<<pgrid, 256, 0, stream>>>(x, Wxr, br, Wxz, bz, Wi, bb, xr, xz, out, bar);
        const __hip_bfloat16* xrc = xr; const __hip_bfloat16* xzc = xz;
        void* args[8] = {(void*)&xrc, (void*)&xzc, (void*)&Whr, (void*)&Whz,
                         (void*)&Wh, (void*)&out, (void*)&hb, (void*)&bar};
        hipLaunchCooperativeKernel((void*)scan_kernel<__hip_bfloat16>, dim3(256), dim3(512),
                                   args, 0, stream);
    } else {
        sentinel_kernel<<<1, 64, 0, stream>>>(out);
    }
}